// Round 5
// baseline (121.543 us; speedup 1.0000x reference)
//
#include <hip/hip_runtime.h>

// IndRNN forward: proj = x @ W + b  (M=B*T, K=D=256, N=U), then
// h_t = relu(proj_t + h_{t-1} * clip(u,0,1)) over T.
// R2..R6 history: fused per-(b, 128-unit) block; bf16 x/W pre-convert;
//   gl_lds w=16 XOR-swizzled A staging; W-frags in VGPRs; proj in separate
//   LDS buffer, transposed [u][t] with 16B-granule XOR swizzle; b128 scan.
//   R4: 2 blocks/CU neutral. R5: in-kernel fp32 convert regressed (reverted).
//   R6: barrier 3->2, transposed proj: 122 -> 118.7 total, fused ~24 us.
// R7: PRODUCER-CONSUMER WAVE SPECIALIZATION. No s_barrier in the main loop.
//   waves 2-3 (producers, t-split: w2 owns t0-31, w3 t32-63, ALL 128 units):
//     stage own Xs rows (wave-local, double-buffered) -> MFMA -> proj into
//     double-buffered P. Xs needs NO cross-wave sync (each producer stages
//     and reads only its own rows). bfr[8][8]=256 VGPR + acc[2][8]=64.
//   waves 0-1 (consumers): spin on rdy flags -> b128-read P -> 64-step scan
//     -> out stores -> set fre flags.
//   Flags: monotonic ints in LDS; producer chunk c waits fre*[c&1] >= c-1
//   (consumer done with c-2), sets rdy_w[c&1]=c+1 after lgkmcnt(0);
//   consumer waits rdy2&rdy3 >= c+1, sets fre_w[c&1]=c+1.
//   => MFMA stream and scan stream overlap: wall ~= max, not sum.
//   Also: conv_x + conv_wt merged into one launch (one fewer gap).

__device__ __forceinline__ unsigned short f2bf(float f) {
    unsigned int u = __float_as_uint(f);
    unsigned int r = (u + 0x7FFF + ((u >> 16) & 1)) >> 16;  // RNE
    return (unsigned short)r;
}

typedef __bf16 bf16x8 __attribute__((ext_vector_type(8)));
typedef float f32x4 __attribute__((ext_vector_type(4)));

typedef const unsigned char __attribute__((address_space(1))) gc_t;
typedef unsigned char __attribute__((address_space(3))) lds_t;

__device__ __forceinline__ void gl_lds16(const void* g, void* l) {
    __builtin_amdgcn_global_load_lds((gc_t*)g, (lds_t*)l, 16, 0, 0);
}

// ------------------------------------------------------------ conversion
__global__ __launch_bounds__(256) void conv_xw(
    const float* __restrict__ x, unsigned short* __restrict__ xb, int n4,
    const float* __restrict__ W, unsigned short* __restrict__ Wt,
    int K, int N, int xblocks)
{
    if ((int)blockIdx.x < xblocks) {
        int i = blockIdx.x * 256 + threadIdx.x;
        if (i >= n4) return;
        float4 v = *(const float4*)(x + (long)i * 4);
        ushort4 o;
        o.x = f2bf(v.x); o.y = f2bf(v.y); o.z = f2bf(v.z); o.w = f2bf(v.w);
        *(ushort4*)(xb + (long)i * 4) = o;
    } else {
        int idx = (blockIdx.x - xblocks) * 256 + threadIdx.x;
        int kq = K >> 2;
        if (idx >= N * kq) return;
        int n = idx / kq;
        int k4 = (idx - n * kq) * 4;
        ushort4 o;
        o.x = f2bf(W[(long)(k4 + 0) * N + n]);
        o.y = f2bf(W[(long)(k4 + 1) * N + n]);
        o.z = f2bf(W[(long)(k4 + 2) * N + n]);
        o.w = f2bf(W[(long)(k4 + 3) * N + n]);
        *(ushort4*)(Wt + (long)n * K + k4) = o;
    }
}

// ------------------------------------------------------------ fused kernel
// Requires D == 256, U % 128 == 0, T % 64 == 0.
#define TC 64    // timesteps per chunk
#define GN 128   // units per block

__global__ __launch_bounds__(256, 1) void indrnn_fused(
    const unsigned short* __restrict__ xb,   // bf16 [B*T, 256]
    const unsigned short* __restrict__ wt,   // bf16 [U, 256]  (W^T)
    const float* __restrict__ bias,          // [U]
    const float* __restrict__ h0,            // [B, U]
    const float* __restrict__ uvec,          // [U]
    float* __restrict__ out,                 // [B, T, U]
    int B, int T, int U)
{
    __shared__ char Xs[2][TC * 512];         // 2 x 32 KB bf16 A chunks (dbuf)
    __shared__ char Ps[2][GN * TC * 4];      // 2 x 32 KB fp32 proj [u][t] (dbuf)
    __shared__ int  flg[8];                  // [0..1] rdy_w2, [2..3] rdy_w3,
                                             // [4..5] fre_w0, [6..7] fre_w1

    const int tid  = threadIdx.x;
    const int lane = tid & 63;
    const int w    = tid >> 6;     // wave 0..3
    const int m    = lane & 15;
    const int quad = lane >> 4;    // 0..3
    const int b    = blockIdx.x;
    const int n0   = blockIdx.y * GN;

    if (tid < 8) flg[tid] = 0;
    __syncthreads();               // the ONLY block-wide barrier

    volatile int* vf = (volatile int*)flg;
    const int nch = T / TC;

    if (w >= 2) {
        // ==================== PRODUCER (waves 2,3) ====================
        const int r0 = (w - 2) * 32;          // own t-rows r0..r0+31
        const int p  = lane & 31;
        const int hh = lane >> 5;
        const unsigned short* xrow = xb + (long)b * T * 256;

        // W fragments: all 128 units. 8 col-tiles x 8 k-steps x 16B = 256 VGPR.
        bf16x8 bfr[8][8];
#pragma unroll
        for (int j = 0; j < 8; ++j)
#pragma unroll
            for (int kt = 0; kt < 8; ++kt)
                bfr[j][kt] = *(const bf16x8*)(
                    wt + (long)(n0 + j * 16 + m) * 256 + kt * 32 + quad * 8);

        float bb[8];
#pragma unroll
        for (int j = 0; j < 8; ++j) bb[j] = bias[n0 + j * 16 + m];

        // prologue: stage own rows of chunk 0 into Xs[0]
#pragma unroll
        for (int l = 0; l < 16; ++l) {
            int row = r0 + l * 2 + hh;
            int gp  = p ^ (row & 15);
            gl_lds16(xrow + (long)row * 256 + gp * 8,
                     &Xs[0][r0 * 512 + l * 1024]);
        }

        for (int c = 0; c < nch; ++c) {
            const int buf = c & 1, nb = buf ^ 1;

            // DMA for chunk c (issued prev iter / prologue) must be complete.
            asm volatile("s_waitcnt vmcnt(0)" ::: "memory");
            __builtin_amdgcn_sched_barrier(0);

            // issue DMA for chunk c+1 into Xs[nb] (own rows; wave-local,
            // Xs[nb] was last read by THIS wave's MFMA of chunk c-1).
            if (c + 1 < nch) {
                const unsigned short* gb = xrow + (long)(c + 1) * TC * 256;
#pragma unroll
                for (int l = 0; l < 16; ++l) {
                    int row = r0 + l * 2 + hh;
                    int gp  = p ^ (row & 15);
                    gl_lds16(gb + (long)row * 256 + gp * 8,
                             &Xs[nb][r0 * 512 + l * 1024]);
                }
            }

            // MFMA: own 32 t-rows x 128 units from Xs[buf]
            f32x4 acc[2][8];
#pragma unroll
            for (int i = 0; i < 2; ++i)
#pragma unroll
                for (int j = 0; j < 8; ++j) acc[i][j] = (f32x4){0.f, 0.f, 0.f, 0.f};

#pragma unroll
            for (int kt = 0; kt < 8; ++kt) {
                const int off = (((kt * 4 + quad) ^ m) * 16);
                bf16x8 a0 = *(const bf16x8*)(&Xs[buf][(r0 + m) * 512 + off]);
                bf16x8 a1 = *(const bf16x8*)(&Xs[buf][(r0 + 16 + m) * 512 + off]);
#pragma unroll
                for (int j = 0; j < 8; ++j) {
                    acc[0][j] = __builtin_amdgcn_mfma_f32_16x16x32_bf16(
                        a0, bfr[j][kt], acc[0][j], 0, 0, 0);
                    acc[1][j] = __builtin_amdgcn_mfma_f32_16x16x32_bf16(
                        a1, bfr[j][kt], acc[1][j], 0, 0, 0);
                }
            }

            // wait until BOTH consumers freed P[buf] (done with chunk c-2)
            while (vf[4 + buf] < c - 1 || vf[6 + buf] < c - 1) {}
            asm volatile("" ::: "memory");
            __builtin_amdgcn_sched_barrier(0);

            // proj (+bias) -> P[buf], transposed [u][t], 16B-granule XOR swz
#pragma unroll
            for (int i = 0; i < 2; ++i)
#pragma unroll
                for (int j = 0; j < 8; ++j) {
                    f32x4 v = acc[i][j];
                    f32x4 vb = {v[0] + bb[j], v[1] + bb[j],
                                v[2] + bb[j], v[3] + bb[j]};
                    int col = j * 16 + m;
                    int g   = (r0 >> 2) + i * 4 + quad;   // (t-row)>>2
                    *(f32x4*)(&Ps[buf][col * 256 + (((g ^ (col & 7)) << 4))]) = vb;
                }
            asm volatile("s_waitcnt lgkmcnt(0)" ::: "memory");
            if (lane == 0) vf[(w - 2) * 2 + buf] = c + 1;   // rdy
        }
    } else {
        // ==================== CONSUMER (waves 0,1) ====================
        const float uc = fminf(fmaxf(uvec[n0 + tid], 0.0f), 1.0f);
        float h = h0[(long)b * U + n0 + tid];
        const int ub = tid * 256;
        const int ux = (tid & 7) << 4;

        for (int c = 0; c < nch; ++c) {
            const int buf = c & 1;

            // wait until BOTH producers published proj chunk c
            while (vf[0 + buf] < c + 1 || vf[2 + buf] < c + 1) {}
            asm volatile("" ::: "memory");
            __builtin_amdgcn_sched_barrier(0);

            f32x4 pv[16];
#pragma unroll
            for (int gg = 0; gg < 16; ++gg)
                pv[gg] = *(const f32x4*)(&Ps[buf][ub + ((gg << 4) ^ ux)]);

            float* og = out + ((long)b * T + c * TC) * U + n0 + tid;
#pragma unroll
            for (int gg = 0; gg < 16; ++gg)
#pragma unroll
                for (int e = 0; e < 4; ++e) {
                    h = fmaxf(fmaf(h, uc, pv[gg][e]), 0.0f);
                    og[(long)(gg * 4 + e) * U] = h;
                }

            asm volatile("s_waitcnt lgkmcnt(0)" ::: "memory");
            if (lane == 0) vf[4 + w * 2 + buf] = c + 1;     // fre
        }
    }
}

// ------------------------------------------------------------ fp32 fallback
#define BM 128
#define BN 128
#define BK 8

__global__ __launch_bounds__(256) void indrnn_gemm_bias(
    const float* __restrict__ A, const float* __restrict__ Bm,
    const float* __restrict__ bias, float* __restrict__ C,
    int M, int N, int K)
{
    __shared__ float As[BK][BM];
    __shared__ float Bs[BK][BN];
    const int tid = threadIdx.x;
    const int row0 = blockIdx.x * BM, col0 = blockIdx.y * BN;
    const int tx = tid & 15, ty = tid >> 4;
    float acc[8][8];
#pragma unroll
    for (int i = 0; i < 8; ++i)
#pragma unroll
        for (int j = 0; j < 8; ++j) acc[i][j] = 0.0f;
    const int am = tid >> 1, ak = (tid & 1) * 4;
    const int bk = tid >> 5, bn = (tid & 31) * 4;
    const float* Aptr = A + (long)(row0 + am) * K + ak;
    const float* Bptr = Bm + (long)bk * N + col0 + bn;
    for (int kt = 0; kt < K; kt += BK) {
        float4 av = *(const float4*)(Aptr + kt);
        float4 bv = *(const float4*)(Bptr + (long)kt * N);
        As[ak + 0][am] = av.x; As[ak + 1][am] = av.y;
        As[ak + 2][am] = av.z; As[ak + 3][am] = av.w;
        *(float4*)&Bs[bk][bn] = bv;
        __syncthreads();
#pragma unroll
        for (int k = 0; k < BK; ++k) {
            float4 a0 = *(const float4*)&As[k][ty * 4];
            float4 a1 = *(const float4*)&As[k][64 + ty * 4];
            float4 b0 = *(const float4*)&Bs[k][tx * 4];
            float4 b1 = *(const float4*)&Bs[k][64 + tx * 4];
            float a[8] = {a0.x, a0.y, a0.z, a0.w, a1.x, a1.y, a1.z, a1.w};
            float bb2[8] = {b0.x, b0.y, b0.z, b0.w, b1.x, b1.y, b1.z, b1.w};
#pragma unroll
            for (int i = 0; i < 8; ++i)
#pragma unroll
                for (int j = 0; j < 8; ++j)
                    acc[i][j] = fmaf(a[i], bb2[j], acc[i][j]);
        }
        __syncthreads();
    }
    float bb[8];
#pragma unroll
    for (int j = 0; j < 4; ++j) {
        bb[j] = bias[col0 + tx * 4 + j];
        bb[j + 4] = bias[col0 + 64 + tx * 4 + j];
    }
#pragma unroll
    for (int i = 0; i < 8; ++i) {
        const int r = (i < 4) ? (ty * 4 + i) : (64 + ty * 4 + (i - 4));
        float* crow = C + (long)(row0 + r) * N + col0;
        float4 v0 = {acc[i][0] + bb[0], acc[i][1] + bb[1], acc[i][2] + bb[2], acc[i][3] + bb[3]};
        float4 v1 = {acc[i][4] + bb[4], acc[i][5] + bb[5], acc[i][6] + bb[6], acc[i][7] + bb[7]};
        *(float4*)(crow + tx * 4) = v0;
        *(float4*)(crow + 64 + tx * 4) = v1;
    }
}

#define SCAN_UNROLL 32

__global__ __launch_bounds__(256) void indrnn_scan(
    float* __restrict__ out, const float* __restrict__ h0,
    const float* __restrict__ u, int B, int T, int U)
{
    const int idx = blockIdx.x * blockDim.x + threadIdx.x;
    if (idx >= B * U) return;
    const int b = idx / U;
    const int un = idx - b * U;
    const float uc = fminf(fmaxf(u[un], 0.0f), 1.0f);
    float h = h0[(long)b * U + un];
    float* p = out + (long)b * T * U + un;
    for (int t = 0; t < T; t += SCAN_UNROLL) {
        float pv[SCAN_UNROLL];
#pragma unroll
        for (int i = 0; i < SCAN_UNROLL; ++i)
            pv[i] = p[(long)(t + i) * U];
#pragma unroll
        for (int i = 0; i < SCAN_UNROLL; ++i) {
            h = fmaxf(fmaf(h, uc, pv[i]), 0.0f);
            pv[i] = h;
        }
#pragma unroll
        for (int i = 0; i < SCAN_UNROLL; ++i)
            p[(long)(t + i) * U] = pv[i];
    }
}

// ------------------------------------------------------------ launch
extern "C" void kernel_launch(void* const* d_in, const int* in_sizes, int n_in,
                              void* d_out, int out_size, void* d_ws, size_t ws_size,
                              hipStream_t stream) {
    const float* x  = (const float*)d_in[0]; // [B,T,D]
    const float* h0 = (const float*)d_in[1]; // [B,U]
    const float* W  = (const float*)d_in[2]; // [D,U]
    const float* u  = (const float*)d_in[3]; // [U]
    const float* b  = (const float*)d_in[4]; // [U]
    float* out = (float*)d_out;              // [B,T,U]

    const int U = in_sizes[3];
    const int B = in_sizes[1] / U;
    const int D = in_sizes[2] / U;
    const int T = in_sizes[0] / (B * D);
    const int M = B * T;

    const size_t xb_bytes = (size_t)M * D * sizeof(unsigned short);
    const size_t wt_bytes = (size_t)U * D * sizeof(unsigned short);
    const bool fused_ok = (D == 256) && (U % GN == 0) && (T % TC == 0) &&
                          (ws_size >= xb_bytes + wt_bytes);

    if (fused_ok) {
        unsigned short* xb = (unsigned short*)d_ws;
        unsigned short* wt = (unsigned short*)((char*)d_ws + xb_bytes);

        const int n4 = (M * D) / 4;
        const int nwt = U * (D / 4);
        const int xblocks = (n4 + 255) / 256;
        const int wblocks = (nwt + 255) / 256;
        conv_xw<<<xblocks + wblocks, 256, 0, stream>>>(
            x, xb, n4, W, wt, D, U, xblocks);

        dim3 g(B, U / GN);
        indrnn_fused<<<g, 256, 0, stream>>>(xb, wt, b, h0, u, out, B, T, U);
    } else {
        dim3 ggrid(M / BM, U / BN);
        indrnn_gemm_bias<<<ggrid, 256, 0, stream>>>(x, W, b, out, M, U, D);
        const int nthreads = B * U;
        indrnn_scan<<<(nthreads + 255) / 256, 256, 0, stream>>>(out, h0, u, B, T, U);
    }
}

// Round 6
// 116.449 us; speedup vs baseline: 1.0438x; 1.0438x over previous
//
#include <hip/hip_runtime.h>

// IndRNN forward: proj = x @ W + b  (M=B*T, K=D=256, N=U), then
// h_t = relu(proj_t + h_{t-1} * clip(u,0,1)) over T.
// R2..R6: fused per-(b, 128-unit) block; gl_lds XOR-swizzled A staging;
//   W-frags in VGPRs; proj in separate LDS buffer transposed [u][t] with
//   16B-granule XOR swizzle; b128 scan. R6 = best structure (118.7 us).
// R4: 2 blocks/CU neutral. R5: in-kernel convert via reg-staging regressed
//   (f2bf VALU on store path, serial between barriers). R7: producer-consumer
//   wave split regressed (MFMA on 2 of 4 SIMDs + spin overhead). Reverted.
// R8: ZERO PRE-PASS KERNELS (single launch). R6 structure kept exactly;
//   conversion moved where it's free:
//   - x staged as FP32 via global_load_lds (DMA, no VALU on store path;
//     Xs = 64 KB, 96 KB LDS total, still 1 block/CU). Same XOR granule
//     swizzle (64 granules/row; LDS gran g of row r holds global gran
//     g^(r&15); reader XORs with m == row&15).
//   - A-frags: 2 x f32x4 ds_read + 8 HW __bf16 casts, pipelined under MFMA.
//   - W converted once per block in the prologue from fp32 W (hidden under
//     chunk-0 staging DMA). Saves conv dispatch (~8 us) + launch gap +
//     50 MB HBM round-trip.

typedef __bf16 bf16x8 __attribute__((ext_vector_type(8)));
typedef float f32x4 __attribute__((ext_vector_type(4)));

typedef const unsigned char __attribute__((address_space(1))) gc_t;
typedef unsigned char __attribute__((address_space(3))) lds_t;

__device__ __forceinline__ void gl_lds16(const void* g, void* l) {
    __builtin_amdgcn_global_load_lds((gc_t*)g, (lds_t*)l, 16, 0, 0);
}

__device__ __forceinline__ bf16x8 cvt8(f32x4 lo, f32x4 hi) {
    bf16x8 r;
    r[0] = (__bf16)lo[0]; r[1] = (__bf16)lo[1];
    r[2] = (__bf16)lo[2]; r[3] = (__bf16)lo[3];
    r[4] = (__bf16)hi[0]; r[5] = (__bf16)hi[1];
    r[6] = (__bf16)hi[2]; r[7] = (__bf16)hi[3];
    return r;
}

// ------------------------------------------------------------ fused kernel
// Requires D == 256, U % 128 == 0, T % 64 == 0.
#define TC 64    // timesteps per chunk
#define GN 128   // units per block

__global__ __launch_bounds__(256, 1) void indrnn_fused(
    const float* __restrict__ x,             // fp32 [B*T, 256]
    const float* __restrict__ W,             // fp32 [256, U]
    const float* __restrict__ bias,          // [U]
    const float* __restrict__ h0,            // [B, U]
    const float* __restrict__ uvec,          // [U]
    float* __restrict__ out,                 // [B, T, U]
    int B, int T, int U)
{
    __shared__ char Xs[TC * 1024];           // 64 KB: fp32 A-chunk (single buffer)
    __shared__ char Ps[GN * TC * 4];         // 32 KB: fp32 proj, transposed [u][t]

    const int tid  = threadIdx.x;
    const int lane = tid & 63;
    const int w    = tid >> 6;     // wave 0..3
    const int m    = lane & 15;
    const int quad = lane >> 4;    // 0..3
    const int b    = blockIdx.x;
    const int n0   = blockIdx.y * GN;
    const int tq   = (w >> 1) * 32;   // wave's row quadrant (t-local)
    const int cq   = (w & 1) * 64;    // wave's col quadrant

    const float* xrow = x + (long)b * T * 256;

    // ---- prologue part 1: stage chunk 0 as fp32 (all 4 waves, 16 rows each).
    // One gl_lds16 per row: 64 lanes x 16B = 1024 B = full row. LDS granule
    // l <- global granule (l ^ (row&15)).
#pragma unroll
    for (int i = 0; i < 16; ++i) {
        int row = i * 4 + w;
        int sg  = lane ^ (row & 15);
        gl_lds16(xrow + (long)row * 256 + sg * 4, &Xs[row * 1024]);
    }

    // ---- prologue part 2 (overlaps DMA): W fragments from fp32 W.
    // bfr[j][kt][e] = bf16( W[(kt*32 + quad*8 + e)][n0 + cq + j*16 + m] ).
    bf16x8 bfr[4][8];
#pragma unroll
    for (int j = 0; j < 4; ++j)
#pragma unroll
        for (int kt = 0; kt < 8; ++kt) {
            const float* wp = W + (long)(kt * 32 + quad * 8) * U
                                + (n0 + cq + j * 16 + m);
            bf16x8 f;
#pragma unroll
            for (int e = 0; e < 8; ++e) f[e] = (__bf16)wp[(long)e * U];
            bfr[j][kt] = f;
        }

    float bb[4];
#pragma unroll
    for (int j = 0; j < 4; ++j) bb[j] = bias[n0 + cq + j * 16 + m];

    float uc = 0.0f, h = 0.0f;
    if (tid < GN) {
        uc = fminf(fmaxf(uvec[n0 + tid], 0.0f), 1.0f);
        h  = h0[(long)b * U + n0 + tid];
    }

    asm volatile("s_waitcnt vmcnt(0)" ::: "memory");
    __builtin_amdgcn_sched_barrier(0);
    __syncthreads();   // chunk 0 staged & visible

    const int nch = T / TC;
    for (int c = 0; c < nch; ++c) {
        // ---- MFMA: wave computes 32t x 64u quadrant; A read fp32 from LDS,
        //      converted to bf16 in-register (pipelined across kt).
        f32x4 acc[2][4];
#pragma unroll
        for (int i = 0; i < 2; ++i)
#pragma unroll
            for (int j = 0; j < 4; ++j) acc[i][j] = (f32x4){0.f, 0.f, 0.f, 0.f};

#pragma unroll
        for (int kt = 0; kt < 8; ++kt) {
            // granule index G = kt*8 | quad*2 | half (disjoint bit fields);
            // LDS granule actually read = G ^ m  (m == row&15 for both rows).
            const int g0 = ((kt * 8 + quad * 2 + 0) ^ m) << 4;
            const int g1 = ((kt * 8 + quad * 2 + 1) ^ m) << 4;
            const char* r0p = Xs + (tq + m) * 1024;
            const char* r1p = Xs + (tq + 16 + m) * 1024;
            f32x4 a0lo = *(const f32x4*)(r0p + g0);
            f32x4 a0hi = *(const f32x4*)(r0p + g1);
            f32x4 a1lo = *(const f32x4*)(r1p + g0);
            f32x4 a1hi = *(const f32x4*)(r1p + g1);
            bf16x8 a0 = cvt8(a0lo, a0hi);
            bf16x8 a1 = cvt8(a1lo, a1hi);
#pragma unroll
            for (int j = 0; j < 4; ++j) {
                acc[0][j] = __builtin_amdgcn_mfma_f32_16x16x32_bf16(
                    a0, bfr[j][kt], acc[0][j], 0, 0, 0);
                acc[1][j] = __builtin_amdgcn_mfma_f32_16x16x32_bf16(
                    a1, bfr[j][kt], acc[1][j], 0, 0, 0);
            }
        }

        // ---- proj (+bias) -> P, transposed [u][t], 16B-granule XOR swizzle.
#pragma unroll
        for (int i = 0; i < 2; ++i)
#pragma unroll
            for (int j = 0; j < 4; ++j) {
                f32x4 v = acc[i][j];
                f32x4 vb = {v[0] + bb[j], v[1] + bb[j], v[2] + bb[j], v[3] + bb[j]};
                int col = cq + j * 16 + m;
                int g   = (tq >> 2) + i * 4 + quad;   // (t-row)>>2
                *(f32x4*)(Ps + col * 256 + (((g ^ (col & 7)) << 4))) = vb;
            }
        __syncthreads();   // proj visible; all MFMA reads of Xs done block-wide

        // ---- issue staging of chunk c+1 into Xs (uniform, all 4 waves).
        // Safe: every wave's reads of Xs completed before the barrier.
        // DMA latency hides under the scan; drained before next top barrier.
        if (c + 1 < nch) {
            const float* gb = xrow + (long)(c + 1) * TC * 256;
#pragma unroll
            for (int i = 0; i < 16; ++i) {
                int row = i * 4 + w;
                int sg  = lane ^ (row & 15);
                gl_lds16(gb + (long)row * 256 + sg * 4, &Xs[row * 1024]);
            }
        }

        // ---- waves 0-1: sequential scan of chunk c from P (b128 reads)
        if (tid < GN) {
            f32x4 pv[16];
            const int ub = tid * 256;
            const int ux = (tid & 7) << 4;
#pragma unroll
            for (int gg = 0; gg < 16; ++gg)
                pv[gg] = *(const f32x4*)(Ps + ub + ((gg << 4) ^ ux));
            float* og = out + ((long)b * T + c * TC) * U + n0 + tid;
#pragma unroll
            for (int gg = 0; gg < 16; ++gg)
#pragma unroll
                for (int e = 0; e < 4; ++e) {
                    h = fmaxf(fmaf(h, uc, pv[gg][e]), 0.0f);
                    og[(long)(gg * 4 + e) * U] = h;
                }
        }

        // ---- drain staging DMA explicitly, then barrier (race fix, R3).
        asm volatile("s_waitcnt vmcnt(0)" ::: "memory");
        __builtin_amdgcn_sched_barrier(0);
        __syncthreads();   // chunk c+1 staged; P free for next proj
    }
}

// ------------------------------------------------------------ fp32 fallback
#define BM 128
#define BN 128
#define BK 8

__global__ __launch_bounds__(256) void indrnn_gemm_bias(
    const float* __restrict__ A, const float* __restrict__ Bm,
    const float* __restrict__ bias, float* __restrict__ C,
    int M, int N, int K)
{
    __shared__ float As[BK][BM];
    __shared__ float Bs[BK][BN];
    const int tid = threadIdx.x;
    const int row0 = blockIdx.x * BM, col0 = blockIdx.y * BN;
    const int tx = tid & 15, ty = tid >> 4;
    float acc[8][8];
#pragma unroll
    for (int i = 0; i < 8; ++i)
#pragma unroll
        for (int j = 0; j < 8; ++j) acc[i][j] = 0.0f;
    const int am = tid >> 1, ak = (tid & 1) * 4;
    const int bk = tid >> 5, bn = (tid & 31) * 4;
    const float* Aptr = A + (long)(row0 + am) * K + ak;
    const float* Bptr = Bm + (long)bk * N + col0 + bn;
    for (int kt = 0; kt < K; kt += BK) {
        float4 av = *(const float4*)(Aptr + kt);
        float4 bv = *(const float4*)(Bptr + (long)kt * N);
        As[ak + 0][am] = av.x; As[ak + 1][am] = av.y;
        As[ak + 2][am] = av.z; As[ak + 3][am] = av.w;
        *(float4*)&Bs[bk][bn] = bv;
        __syncthreads();
#pragma unroll
        for (int k = 0; k < BK; ++k) {
            float4 a0 = *(const float4*)&As[k][ty * 4];
            float4 a1 = *(const float4*)&As[k][64 + ty * 4];
            float4 b0 = *(const float4*)&Bs[k][tx * 4];
            float4 b1 = *(const float4*)&Bs[k][64 + tx * 4];
            float a[8] = {a0.x, a0.y, a0.z, a0.w, a1.x, a1.y, a1.z, a1.w};
            float bb2[8] = {b0.x, b0.y, b0.z, b0.w, b1.x, b1.y, b1.z, b1.w};
#pragma unroll
            for (int i = 0; i < 8; ++i)
#pragma unroll
                for (int j = 0; j < 8; ++j)
                    acc[i][j] = fmaf(a[i], bb2[j], acc[i][j]);
        }
        __syncthreads();
    }
    float bb[8];
#pragma unroll
    for (int j = 0; j < 4; ++j) {
        bb[j] = bias[col0 + tx * 4 + j];
        bb[j + 4] = bias[col0 + 64 + tx * 4 + j];
    }
#pragma unroll
    for (int i = 0; i < 8; ++i) {
        const int r = (i < 4) ? (ty * 4 + i) : (64 + ty * 4 + (i - 4));
        float* crow = C + (long)(row0 + r) * N + col0;
        float4 v0 = {acc[i][0] + bb[0], acc[i][1] + bb[1], acc[i][2] + bb[2], acc[i][3] + bb[3]};
        float4 v1 = {acc[i][4] + bb[4], acc[i][5] + bb[5], acc[i][6] + bb[6], acc[i][7] + bb[7]};
        *(float4*)(crow + tx * 4) = v0;
        *(float4*)(crow + 64 + tx * 4) = v1;
    }
}

#define SCAN_UNROLL 32

__global__ __launch_bounds__(256) void indrnn_scan(
    float* __restrict__ out, const float* __restrict__ h0,
    const float* __restrict__ u, int B, int T, int U)
{
    const int idx = blockIdx.x * blockDim.x + threadIdx.x;
    if (idx >= B * U) return;
    const int b = idx / U;
    const int un = idx - b * U;
    const float uc = fminf(fmaxf(u[un], 0.0f), 1.0f);
    float h = h0[(long)b * U + un];
    float* p = out + (long)b * T * U + un;
    for (int t = 0; t < T; t += SCAN_UNROLL) {
        float pv[SCAN_UNROLL];
#pragma unroll
        for (int i = 0; i < SCAN_UNROLL; ++i)
            pv[i] = p[(long)(t + i) * U];
#pragma unroll
        for (int i = 0; i < SCAN_UNROLL; ++i) {
            h = fmaxf(fmaf(h, uc, pv[i]), 0.0f);
            pv[i] = h;
        }
#pragma unroll
        for (int i = 0; i < SCAN_UNROLL; ++i)
            p[(long)(t + i) * U] = pv[i];
    }
}

// ------------------------------------------------------------ launch
extern "C" void kernel_launch(void* const* d_in, const int* in_sizes, int n_in,
                              void* d_out, int out_size, void* d_ws, size_t ws_size,
                              hipStream_t stream) {
    const float* x  = (const float*)d_in[0]; // [B,T,D]
    const float* h0 = (const float*)d_in[1]; // [B,U]
    const float* W  = (const float*)d_in[2]; // [D,U]
    const float* u  = (const float*)d_in[3]; // [U]
    const float* b  = (const float*)d_in[4]; // [U]
    float* out = (float*)d_out;              // [B,T,U]

    const int U = in_sizes[3];
    const int B = in_sizes[1] / U;
    const int D = in_sizes[2] / U;
    const int T = in_sizes[0] / (B * D);
    const int M = B * T;

    const bool fused_ok = (D == 256) && (U % GN == 0) && (T % TC == 0);

    if (fused_ok) {
        dim3 g(B, U / GN);
        indrnn_fused<<<g, 256, 0, stream>>>(x, W, b, h0, u, out, B, T, U);
    } else {
        dim3 ggrid(M / BM, U / BN);
        indrnn_gemm_bias<<<ggrid, 256, 0, stream>>>(x, W, b, out, M, U, D);
        const int nthreads = B * U;
        indrnn_scan<<<(nthreads + 255) / 256, 256, 0, stream>>>(out, h0, u, B, T, U);
    }
}